// Round 4
// baseline (82.390 us; speedup 1.0000x reference)
//
#include <hip/hip_runtime.h>
#include <stdint.h>

#define N 4096
#define D 512
#define TILE 128
#define BK 128           // fp8 bytes (=elems) per K-chunk
#define KITERS (D / BK)  // 4
#define NB (N / TILE)    // 32
#define NOFF (NB * (NB - 1) / 2)  // 496 strict-lower block pairs
#define NBLK (NB * (NB + 1) / 2)  // 528 total blocks

typedef float f32x4 __attribute__((ext_vector_type(4)));
typedef int   i32x8 __attribute__((ext_vector_type(8)));
typedef int   i32x4 __attribute__((ext_vector_type(4)));

// ---------------------------------------------------------------------------
// Kernel 1: fp32 -> fp8 e4m3 (OCP) conversion + fp32 row squared-norms.
// One wave per row: 512 elems / 64 lanes = 8 elems/lane (one 8B store).
// Norms are exact fp32; only the Gram term carries fp8 error.
// ---------------------------------------------------------------------------
__global__ __launch_bounds__(256) void prep_kernel(const float* __restrict__ x,
                                                   unsigned char* __restrict__ xq,
                                                   float* __restrict__ sq) {
    int row  = blockIdx.x * 4 + (threadIdx.x >> 6);
    int lane = threadIdx.x & 63;
    const float* xr = x + (size_t)row * D + lane * 8;
    float4 v0 = *reinterpret_cast<const float4*>(xr);
    float4 v1 = *reinterpret_cast<const float4*>(xr + 4);

    int w0 = __builtin_amdgcn_cvt_pk_fp8_f32(v0.x, v0.y, 0, false);
    w0     = __builtin_amdgcn_cvt_pk_fp8_f32(v0.z, v0.w, w0, true);
    int w1 = __builtin_amdgcn_cvt_pk_fp8_f32(v1.x, v1.y, 0, false);
    w1     = __builtin_amdgcn_cvt_pk_fp8_f32(v1.z, v1.w, w1, true);
    reinterpret_cast<int2*>(xq + (size_t)row * D)[lane] = make_int2(w0, w1);

    float s = v0.x * v0.x + v0.y * v0.y + v0.z * v0.z + v0.w * v0.w +
              v1.x * v1.x + v1.y * v1.y + v1.z * v1.z + v1.w * v1.w;
    #pragma unroll
    for (int off = 32; off > 0; off >>= 1) s += __shfl_down(s, off);
    if (lane == 0) sq[row] = s;
}

// ---------------------------------------------------------------------------
// Kernel 2: lower-triangle Gram via MX-scaled fp8 MFMA (K=128, unit scales)
// + fused distance epilogue. 128x128 tile.
//
// v5: wave-pressure round. v4 (256 thr, 3 blk/CU) confirmed stall-bound +
// TLP-sensitive (-4 us). But grid wave pressure was only 528*4/1024 = 2.06
// waves/SIMD — capacity beyond that is idle. Fix: put more waves IN THE GRID.
//  - 512-thread blocks, 8 waves; each wave owns a 32x64 sub-tile
//    (wm = w>>1 in 0..3 -> 32-row strip; wn = w&1 -> 64-col strip).
//  - Per-wave regs: acc[2][4]=32, af[2]=16, bfr[4]=32 (all resident, no
//    streaming), ~100 total -> fits 128-VGPR cap of launch_bounds(512,4)
//    -> 4 waves/SIMD; actual pressure 528*8/1024 = 4.1 waves/SIMD (2x v4).
//  - Same single-buffer 2-barrier K-loop (v3 proved dbuf is null), same
//    XOR swizzle, diag-last remap, v_sqrt_f32, cached stores.
//  - 16-block tail (528 > 2/CU*256) = last 16 diag blocks, the cheapest.
//
// LDS swizzle: row stride 128 B == 32 banks; glds forces contiguous LDS
// placement, so we XOR-swizzle the GLOBAL source address per lane: LDS slot
// (row, chunk) holds global 16B-chunk (chunk ^ (row&7)). Fragment reads then
// hit all 8 four-bank groups evenly -> LDS reads at the 8-clk/b128 BW floor.
// ---------------------------------------------------------------------------
__global__ __launch_bounds__(512, 4) void pairdist_kernel(const unsigned char* __restrict__ xq,
                                                          const float* __restrict__ sq,
                                                          float* __restrict__ out) {
    __shared__ __align__(16) unsigned char As[TILE * BK];  // 16 KB
    __shared__ __align__(16) unsigned char Bs[TILE * BK];  // 16 KB

    // Block map: t < NOFF -> strict lower-tri pair (bi > bj); t >= NOFF ->
    // diagonal (bi == bj), launched last (cheapest blocks in the tail round).
    int t = blockIdx.x;
    int bi, bj;
    if (t >= NOFF) {
        bi = bj = t - NOFF;
    } else {
        bi = (int)((sqrtf(8.0f * (float)t + 1.0f) + 1.0f) * 0.5f);
        while (bi * (bi - 1) / 2 > t) bi--;
        while ((bi + 1) * bi / 2 <= t) bi++;
        bj = t - bi * (bi - 1) / 2;
    }

    int tid  = threadIdx.x;
    int w    = tid >> 6;        // wave 0..7
    int lane = tid & 63;
    int quad = lane >> 4;       // 0..3
    int lr   = lane & 15;       // 0..15
    int wm   = w >> 1;          // wave row strip (0..3) -> 32 rows
    int wn   = w & 1;           // wave col strip (0..1) -> 64 cols

    // Diagonal blocks: waves (wm<2, wn=1) cover rows [0,64) x cols [64,128):
    // all j > i, zero outputs -> skip fragment reads + MFMAs entirely.
    // (They still stage their rows and hit every barrier.)
    const bool active = (bi != bj) || (wn == 0) || (wm >= 2);

    // Staging: wave w stages rows [w*16, w*16+16) of each 128x128B panel via
    // 2 glds per panel (8 rows each). lane l -> row l>>3, chunk l&7 in LDS;
    // source chunk = (l&7) ^ (l>>3)  (row&7 == l>>3): the XOR swizzle.
    int srow   = lane >> 3;                 // 0..7
    int schunk = lane & 7;                  // 16B chunk
    int sw     = ((schunk ^ srow) << 4);    // swizzled byte offset in row
    const unsigned char* ga = xq + (size_t)(bi * TILE + w * 16 + srow) * D + sw;
    const unsigned char* gb = xq + (size_t)(bj * TILE + w * 16 + srow) * D + sw;
    unsigned char* la = As + w * 16 * BK;   // wave-uniform LDS bases
    unsigned char* lb = Bs + w * 16 * BK;

    f32x4 acc[2][4];
    #pragma unroll
    for (int mt = 0; mt < 2; mt++)
        #pragma unroll
        for (int nt = 0; nt < 4; nt++)
            acc[mt][nt] = (f32x4)0.0f;

    for (int k0 = 0; k0 < D; k0 += BK) {
        __syncthreads();   // prev iter's ds_reads done before overwrite
        #pragma unroll
        for (int g = 0; g < 2; g++) {
            __builtin_amdgcn_global_load_lds(
                (const __attribute__((address_space(1))) void*)(ga + k0 + (size_t)g * 8 * D),
                (__attribute__((address_space(3))) void*)(la + g * 8 * BK), 16, 0, 0);
            __builtin_amdgcn_global_load_lds(
                (const __attribute__((address_space(1))) void*)(gb + k0 + (size_t)g * 8 * D),
                (__attribute__((address_space(3))) void*)(lb + g * 8 * BK), 16, 0, 0);
        }
        __syncthreads();   // drains vmcnt(0): staging visible

        if (active) {
            // Fragment layout (16x16x128 f8f6f4): lane holds A[m=lr][k=quad*32+j],
            // 32 B = 2 x b128. Swizzle: global chunk m lives at LDS chunk
            // m ^ (lr&7); chunks 2q and 2q+1 -> c0 and c0^16.
            int c0 = (((2 * quad) ^ (lr & 7)) << 4);
            int c1 = c0 ^ 16;

            i32x8 af[2], bfr[4];
            #pragma unroll
            for (int mt = 0; mt < 2; mt++) {
                const unsigned char* rb = As + (wm * 32 + mt * 16 + lr) * BK;
                i32x4 lo = *reinterpret_cast<const i32x4*>(rb + c0);
                i32x4 hi = *reinterpret_cast<const i32x4*>(rb + c1);
                af[mt][0] = lo[0]; af[mt][1] = lo[1]; af[mt][2] = lo[2]; af[mt][3] = lo[3];
                af[mt][4] = hi[0]; af[mt][5] = hi[1]; af[mt][6] = hi[2]; af[mt][7] = hi[3];
            }
            #pragma unroll
            for (int nt = 0; nt < 4; nt++) {
                const unsigned char* rb = Bs + (wn * 64 + nt * 16 + lr) * BK;
                i32x4 lo = *reinterpret_cast<const i32x4*>(rb + c0);
                i32x4 hi = *reinterpret_cast<const i32x4*>(rb + c1);
                bfr[nt][0] = lo[0]; bfr[nt][1] = lo[1]; bfr[nt][2] = lo[2]; bfr[nt][3] = lo[3];
                bfr[nt][4] = hi[0]; bfr[nt][5] = hi[1]; bfr[nt][6] = hi[2]; bfr[nt][7] = hi[3];
            }

            #pragma unroll
            for (int mt = 0; mt < 2; mt++)
                #pragma unroll
                for (int nt = 0; nt < 4; nt++)
                    acc[mt][nt] = __builtin_amdgcn_mfma_scale_f32_16x16x128_f8f6f4(
                        af[mt], bfr[nt], acc[mt][nt],
                        0, 0,                 // cbsz=0 (A fp8 e4m3), blgp=0 (B fp8 e4m3)
                        0, 0x7F7F7F7F,        // A scale: e8m0 127 = x1.0
                        0, 0x7F7F7F7F);       // B scale: x1.0
        }
    }

    // Epilogue: D[m][n] at lane: n = lane&15, m = quad*4 + reg (shape-
    // determined C/D layout — same as 16x16 bf16). sq loads here (once per
    // block) stay out of the K-loop's live range.
    int ibase = bi * TILE + wm * 32;
    int jbase = bj * TILE + wn * 64;

    float sqi[2][4], sqj[4];
    #pragma unroll
    for (int mt = 0; mt < 2; mt++)
        #pragma unroll
        for (int tt = 0; tt < 4; tt++)
            sqi[mt][tt] = sq[ibase + mt * 16 + quad * 4 + tt];
    #pragma unroll
    for (int nt = 0; nt < 4; nt++)
        sqj[nt] = sq[jbase + nt * 16 + lr];

    if (bi != bj) {
        // Fully-below-diagonal block: all j < i guaranteed -> no predicate
        #pragma unroll
        for (int mt = 0; mt < 2; mt++) {
            #pragma unroll
            for (int tt = 0; tt < 4; tt++) {
                int i = ibase + mt * 16 + quad * 4 + tt;
                unsigned rowoff = (unsigned)(i * (i - 1) / 2);
                #pragma unroll
                for (int nt = 0; nt < 4; nt++) {
                    int j = jbase + nt * 16 + lr;
                    float d2 = sqi[mt][tt] + sqj[nt] - 2.0f * acc[mt][nt][tt];
                    out[rowoff + (unsigned)j] = __builtin_amdgcn_sqrtf(fmaxf(d2, 0.0f));
                }
            }
        }
    } else if (active) {
        #pragma unroll
        for (int mt = 0; mt < 2; mt++) {
            #pragma unroll
            for (int tt = 0; tt < 4; tt++) {
                int i = ibase + mt * 16 + quad * 4 + tt;
                unsigned rowoff = (unsigned)(i * (i - 1) / 2);
                #pragma unroll
                for (int nt = 0; nt < 4; nt++) {
                    int j = jbase + nt * 16 + lr;
                    if (j < i) {
                        float d2 = sqi[mt][tt] + sqj[nt] - 2.0f * acc[mt][nt][tt];
                        out[rowoff + (unsigned)j] = __builtin_amdgcn_sqrtf(fmaxf(d2, 0.0f));
                    }
                }
            }
        }
    }
}

extern "C" void kernel_launch(void* const* d_in, const int* in_sizes, int n_in,
                              void* d_out, int out_size, void* d_ws, size_t ws_size,
                              hipStream_t stream) {
    const float* x = (const float*)d_in[0];
    float* out = (float*)d_out;

    // Workspace layout: [0, 2MB) fp8 copy of x; then 16KB of fp32 row norms.
    unsigned char* xq = (unsigned char*)d_ws;
    float* sq = (float*)((char*)d_ws + (size_t)N * D);

    prep_kernel<<<N / 4, 256, 0, stream>>>(x, xq, sq);

    pairdist_kernel<<<NBLK, 512, 0, stream>>>(xq, sq, out);
}

// Round 5
// 81.275 us; speedup vs baseline: 1.0137x; 1.0137x over previous
//
#include <hip/hip_runtime.h>
#include <stdint.h>

#define N 4096
#define D 512
#define BK 128           // fp8 bytes (=elems) per K-chunk
#define KITERS (D / BK)  // 4
// v6 block geometry: 64 output rows x 128 output cols per block.
#define RG 64            // rows per block
#define CP 128           // cols per block
#define NRG (N / RG)     // 64 row groups
#define NFULL 992        // fully-below-diagonal blocks
#define NPART 64         // diagonal-crossing (predicated) blocks, launched last
#define NBLK (NFULL + NPART)  // 1056

typedef float f32x4 __attribute__((ext_vector_type(4)));
typedef int   i32x8 __attribute__((ext_vector_type(8)));
typedef int   i32x4 __attribute__((ext_vector_type(4)));

// ---------------------------------------------------------------------------
// Kernel 1: fp32 -> fp8 e4m3 (OCP) conversion + fp32 row squared-norms.
// One wave per row: 512 elems / 64 lanes = 8 elems/lane (one 8B store).
// Norms are exact fp32; only the Gram term carries fp8 error.
// ---------------------------------------------------------------------------
__global__ __launch_bounds__(256) void prep_kernel(const float* __restrict__ x,
                                                   unsigned char* __restrict__ xq,
                                                   float* __restrict__ sq) {
    int row  = blockIdx.x * 4 + (threadIdx.x >> 6);
    int lane = threadIdx.x & 63;
    const float* xr = x + (size_t)row * D + lane * 8;
    float4 v0 = *reinterpret_cast<const float4*>(xr);
    float4 v1 = *reinterpret_cast<const float4*>(xr + 4);

    int w0 = __builtin_amdgcn_cvt_pk_fp8_f32(v0.x, v0.y, 0, false);
    w0     = __builtin_amdgcn_cvt_pk_fp8_f32(v0.z, v0.w, w0, true);
    int w1 = __builtin_amdgcn_cvt_pk_fp8_f32(v1.x, v1.y, 0, false);
    w1     = __builtin_amdgcn_cvt_pk_fp8_f32(v1.z, v1.w, w1, true);
    reinterpret_cast<int2*>(xq + (size_t)row * D)[lane] = make_int2(w0, w1);

    float s = v0.x * v0.x + v0.y * v0.y + v0.z * v0.z + v0.w * v0.w +
              v1.x * v1.x + v1.y * v1.y + v1.z * v1.z + v1.w * v1.w;
    #pragma unroll
    for (int off = 32; off > 0; off >>= 1) s += __shfl_down(s, off);
    if (lane == 0) sq[row] = s;
}

// ---------------------------------------------------------------------------
// Kernel 2: lower-triangle Gram via MX-scaled fp8 MFMA + fused distance
// epilogue.
//
// v6: independent-block round. Evidence chain: v3 (intra-block dbuf) null;
// v4 (3 block slots/CU) -4us; v5 (2x waves/SIMD but fewer independent
// blocks) +6us. Conclusion: the stall-hiding unit is the INDEPENDENT BLOCK
// (waves in a block are lockstepped by the per-iter vmcnt(0) barriers).
// v4's 3-slot capacity was starved by the grid (528 blocks = 2.06/CU avg).
// Fix: more blocks in the grid.
//  - 64x128 output tiles: 1056 blocks = 4.1 independent blocks/CU.
//  - 256 threads, 4 waves, each owning 32x64 (acc[2][4] = 32 VGPR;
//    af[2]=16 + bfr[4]=32 resident; ~110 live -> fits 128-VGPR cap).
//  - __launch_bounds__(256, 4): capacity 4 blocks/CU (LDS: 4x24KB=96<=160).
//  - Single-buffer 2-barrier K-loop (v3: dbuf is null), XOR swizzle, glds,
//    v_sqrt_f32, cached stores (NT cost +9.5us in v2).
//  - The 64 diagonal-crossing blocks go LAST: cheap predicated blocks form
//    the 32-block overflow tail. Per-wave classification (full / partial /
//    inactive) replaces the old diag special case.
//
// Block map: row-group ri (64 rows), col-panel cj (128 cols). Full blocks
// (panel entirely below diagonal): for ri=2a -> a panels, ri=2a+1 -> a
// panels; cumulative C(2a)=a(a-1), C(2a+1)=a^2, so t in [a(a-1), a^2) ->
// ri=2a, cj=t-a(a-1); t in [a^2, a(a+1)) -> ri=2a+1, cj=t-a^2. Partial
// block p (0..63): ri=p, cj=p>>1.
//
// LDS swizzle: row stride 128 B == 32 banks; glds forces contiguous LDS
// placement, so we XOR-swizzle the GLOBAL source address per lane: LDS slot
// (row, chunk) holds global 16B-chunk (chunk ^ (row&7)). Fragment reads then
// hit all 8 four-bank groups evenly -> LDS reads at the 8-clk/b128 BW floor.
// ---------------------------------------------------------------------------
__global__ __launch_bounds__(256, 4) void pairdist_kernel(const unsigned char* __restrict__ xq,
                                                          const float* __restrict__ sq,
                                                          float* __restrict__ out) {
    __shared__ __align__(16) unsigned char As[RG * BK];  // 8 KB
    __shared__ __align__(16) unsigned char Bs[CP * BK];  // 16 KB

    int t = blockIdx.x;
    int ri, cj;
    if (t >= NFULL) {
        int p = t - NFULL;       // 0..63: diagonal-crossing blocks, last
        ri = p;
        cj = p >> 1;
    } else {
        int a = (int)((sqrtf(4.0f * (float)t + 1.0f) + 1.0f) * 0.5f);
        while (a * (a - 1) > t) a--;
        while (a * (a + 1) <= t) a++;
        if (t < a * a) { ri = 2 * a;     cj = t - a * (a - 1); }
        else           { ri = 2 * a + 1; cj = t - a * a; }
    }

    int tid  = threadIdx.x;
    int w    = tid >> 6;        // wave 0..3
    int lane = tid & 63;
    int quad = lane >> 4;       // 0..3
    int lr   = lane & 15;       // 0..15
    int wm   = w >> 1;          // row strip (0..1) -> 32 rows
    int wn   = w & 1;           // col strip (0..1) -> 64 cols

    int ibase = ri * RG + wm * 32;
    int jbase = cj * CP + wn * 64;
    // Wave classification vs the diagonal:
    //  - jbase+63 <  ibase    : whole 32x64 sub-tile below diag -> no predicate
    //  - jbase    >  ibase+31 : whole sub-tile above diag -> skip MFMA+stores
    //  - else                 : predicated stores
    const bool active = (jbase <= ibase + 31);

    // Staging: wave w stages A rows [w*16, w*16+16) (2 glds) and B rows
    // [w*32, w*32+32) (4 glds). lane l -> row l>>3, chunk l&7 in LDS;
    // source chunk = (l&7) ^ (l>>3): the XOR swizzle.
    int srow   = lane >> 3;                 // 0..7
    int schunk = lane & 7;                  // 16B chunk
    int sw     = ((schunk ^ srow) << 4);    // swizzled byte offset in row
    const unsigned char* ga = xq + (size_t)(ri * RG + w * 16 + srow) * D + sw;
    const unsigned char* gb = xq + (size_t)(cj * CP + w * 32 + srow) * D + sw;
    unsigned char* la = As + w * 16 * BK;   // wave-uniform LDS bases
    unsigned char* lb = Bs + w * 32 * BK;

    f32x4 acc[2][4];
    #pragma unroll
    for (int mt = 0; mt < 2; mt++)
        #pragma unroll
        for (int nt = 0; nt < 4; nt++)
            acc[mt][nt] = (f32x4)0.0f;

    for (int k0 = 0; k0 < D; k0 += BK) {
        __syncthreads();   // prev iter's ds_reads done before overwrite
        #pragma unroll
        for (int g = 0; g < 2; g++)
            __builtin_amdgcn_global_load_lds(
                (const __attribute__((address_space(1))) void*)(ga + k0 + (size_t)g * 8 * D),
                (__attribute__((address_space(3))) void*)(la + g * 8 * BK), 16, 0, 0);
        #pragma unroll
        for (int g = 0; g < 4; g++)
            __builtin_amdgcn_global_load_lds(
                (const __attribute__((address_space(1))) void*)(gb + k0 + (size_t)g * 8 * D),
                (__attribute__((address_space(3))) void*)(lb + g * 8 * BK), 16, 0, 0);
        __syncthreads();   // drains vmcnt(0): staging visible

        if (active) {
            // Fragment layout (16x16x128 f8f6f4): lane holds A[m=lr][k=quad*32+j],
            // 32 B = 2 x b128. Swizzle: global chunk m lives at LDS chunk
            // m ^ (lr&7); chunks 2q and 2q+1 -> c0 and c0^16.
            int c0 = (((2 * quad) ^ (lr & 7)) << 4);
            int c1 = c0 ^ 16;

            i32x8 af[2], bfr[4];
            #pragma unroll
            for (int mt = 0; mt < 2; mt++) {
                const unsigned char* rb = As + (wm * 32 + mt * 16 + lr) * BK;
                i32x4 lo = *reinterpret_cast<const i32x4*>(rb + c0);
                i32x4 hi = *reinterpret_cast<const i32x4*>(rb + c1);
                af[mt][0] = lo[0]; af[mt][1] = lo[1]; af[mt][2] = lo[2]; af[mt][3] = lo[3];
                af[mt][4] = hi[0]; af[mt][5] = hi[1]; af[mt][6] = hi[2]; af[mt][7] = hi[3];
            }
            #pragma unroll
            for (int nt = 0; nt < 4; nt++) {
                const unsigned char* rb = Bs + (wn * 64 + nt * 16 + lr) * BK;
                i32x4 lo = *reinterpret_cast<const i32x4*>(rb + c0);
                i32x4 hi = *reinterpret_cast<const i32x4*>(rb + c1);
                bfr[nt][0] = lo[0]; bfr[nt][1] = lo[1]; bfr[nt][2] = lo[2]; bfr[nt][3] = lo[3];
                bfr[nt][4] = hi[0]; bfr[nt][5] = hi[1]; bfr[nt][6] = hi[2]; bfr[nt][7] = hi[3];
            }

            #pragma unroll
            for (int mt = 0; mt < 2; mt++)
                #pragma unroll
                for (int nt = 0; nt < 4; nt++)
                    acc[mt][nt] = __builtin_amdgcn_mfma_scale_f32_16x16x128_f8f6f4(
                        af[mt], bfr[nt], acc[mt][nt],
                        0, 0,                 // cbsz=0 (A fp8 e4m3), blgp=0 (B fp8 e4m3)
                        0, 0x7F7F7F7F,        // A scale: e8m0 127 = x1.0
                        0, 0x7F7F7F7F);       // B scale: x1.0
        }
    }

    if (!active) return;

    // Epilogue: D[m][n] at lane: n = lane&15, m = quad*4 + reg (shape-
    // determined C/D layout — same as 16x16 bf16). sq loads here (once per
    // block) stay out of the K-loop's live range.
    float sqi[2][4], sqj[4];
    #pragma unroll
    for (int mt = 0; mt < 2; mt++)
        #pragma unroll
        for (int tt = 0; tt < 4; tt++)
            sqi[mt][tt] = sq[ibase + mt * 16 + quad * 4 + tt];
    #pragma unroll
    for (int nt = 0; nt < 4; nt++)
        sqj[nt] = sq[jbase + nt * 16 + lr];

    if (jbase + 63 < ibase) {
        // Sub-tile fully below diagonal -> no predicate
        #pragma unroll
        for (int mt = 0; mt < 2; mt++) {
            #pragma unroll
            for (int tt = 0; tt < 4; tt++) {
                int i = ibase + mt * 16 + quad * 4 + tt;
                unsigned rowoff = (unsigned)(i * (i - 1) / 2);
                #pragma unroll
                for (int nt = 0; nt < 4; nt++) {
                    int j = jbase + nt * 16 + lr;
                    float d2 = sqi[mt][tt] + sqj[nt] - 2.0f * acc[mt][nt][tt];
                    out[rowoff + (unsigned)j] = __builtin_amdgcn_sqrtf(fmaxf(d2, 0.0f));
                }
            }
        }
    } else {
        #pragma unroll
        for (int mt = 0; mt < 2; mt++) {
            #pragma unroll
            for (int tt = 0; tt < 4; tt++) {
                int i = ibase + mt * 16 + quad * 4 + tt;
                unsigned rowoff = (unsigned)(i * (i - 1) / 2);
                #pragma unroll
                for (int nt = 0; nt < 4; nt++) {
                    int j = jbase + nt * 16 + lr;
                    if (j < i) {
                        float d2 = sqi[mt][tt] + sqj[nt] - 2.0f * acc[mt][nt][tt];
                        out[rowoff + (unsigned)j] = __builtin_amdgcn_sqrtf(fmaxf(d2, 0.0f));
                    }
                }
            }
        }
    }
}

extern "C" void kernel_launch(void* const* d_in, const int* in_sizes, int n_in,
                              void* d_out, int out_size, void* d_ws, size_t ws_size,
                              hipStream_t stream) {
    const float* x = (const float*)d_in[0];
    float* out = (float*)d_out;

    // Workspace layout: [0, 2MB) fp8 copy of x; then 16KB of fp32 row norms.
    unsigned char* xq = (unsigned char*)d_ws;
    float* sq = (float*)((char*)d_ws + (size_t)N * D);

    prep_kernel<<<N / 4, 256, 0, stream>>>(x, xq, sq);

    pairdist_kernel<<<NBLK, 256, 0, stream>>>(xq, sq, out);
}